// Round 3
// baseline (612.948 us; speedup 1.0000x reference)
//
#include <hip/hip_runtime.h>

// 3x3 reflect-padded patch extraction.
// x: [8, 256, 256, 32] f32  ->  out: [8, 256, 256, 288] f32
// out[b,h,w, c*9 + i] = x[b, refl(h + i/3 - 1), refl(w + i%3 - 1), c]
//
// v5: h-pair tiling. Each block emits TWO output rows (h, h+1) from FOUR
// input rows loaded ONCE into registers (12 float4/thread vs 18 for the
// same work in v4 -> -33% load instructions, center rows register-reused
// across the two phases instead of re-read from cache/HBM). All loads issue
// as one upfront burst; stores drain as two long coalesced bursts -> coarser
// read/write phase separation at the memory controller.
//  - still barrier-free: LDS transpose is wave-private (rows 8wv..8wv+7);
//    phase 2 reuses the same LDS quadrant. Safety: per-wave DS ops execute
//    in order, and an empty asm "memory" fence stops the compiler from
//    reordering phase-2 ds_writes above phase-1 ds_reads. Zero instructions.
//  - ph loop fully unrolled so Q[][] indexing is compile-time (no scratch).
//  - nontemporal coalesced float4 stores (write-once output).

#define BB 8
#define HH 256
#define WW 256
#define CC 32
#define TAPS 9
#define OUTC (CC * TAPS)    // 288
#define TW 32               // w-tile per block
#define NTW (WW / TW)       // 8 tiles per row
#define HPB 2               // h rows per block

typedef float f32x4 __attribute__((ext_vector_type(4)));

__device__ __forceinline__ int refl(int i, int n) {
    // np.pad mode='reflect', valid for i in [-1, n]
    return i < 0 ? -i : (i >= n ? 2 * n - 2 - i : i);
}

__global__ __launch_bounds__(256) void patch3x3_v5(
    const float* __restrict__ x, float* __restrict__ out) {
    const int blk = blockIdx.x;
    const int wt = blk % NTW;
    const int hb = (blk / NTW) % (HH / HPB);
    const int b  = blk / (NTW * (HH / HPB));
    const int h  = hb * HPB;
    const int w0 = wt * TW;
    const int t  = threadIdx.x;

    __shared__ float out_lds[TW][OUTC];         // 36864 B -> 4 blocks/CU

    const int p  = t >> 3;      // pixel in tile, 0..31 (wave wv owns 8wv..8wv+7)
    const int cg = t & 7;       // channel group of 4, 0..7
    const int wv = t >> 6;
    const int l  = t & 63;

    // ---- four input row bases: refl(h-1), h, h+1, refl(h+2) ----
    const float* xb = x + (size_t)b * HH * WW * CC;
    const float* rowp[4];
    rowp[0] = xb + (size_t)refl(h - 1, HH) * WW * CC;
    rowp[1] = xb + (size_t)h * WW * CC;
    rowp[2] = xb + (size_t)(h + 1) * WW * CC;
    rowp[3] = xb + (size_t)refl(h + 2, HH) * WW * CC;

    int coff[3];
#pragma unroll
    for (int kj = 0; kj < 3; ++kj)
        coff[kj] = refl(w0 + p + kj - 1, WW) * CC + cg * 4;

    // ---- upfront load burst: 12 float4 per thread, all independent ----
    f32x4 Q[4][3];
#pragma unroll
    for (int r = 0; r < 4; ++r)
#pragma unroll
        for (int kj = 0; kj < 3; ++kj)
            Q[r][kj] = *(const f32x4*)(rowp[r] + coff[kj]);

    // ---- two phases: output rows h and h+1, same LDS quadrant reused ----
#pragma unroll
    for (int ph = 0; ph < HPB; ++ph) {
        // repack (pure register selects) + LDS write in output layout
        // local flat f = cl*9 + i, cl in [0,4), i = 3*ki + kj
#pragma unroll
        for (int m = 0; m < 9; ++m) {
            f32x4 v;
#pragma unroll
            for (int k = 0; k < 4; ++k) {
                const int f  = 4 * m + k;   // compile-time
                const int cl = f / 9;
                const int i  = f % 9;
                const int ki = i / 3;
                const int kj = i % 3;
                v[k] = Q[ph + ki][kj][cl];
            }
            *(f32x4*)&out_lds[p][cg * 36 + 4 * m] = v;
        }

        // wave reads back only its own quadrant; no barrier needed
        f32x4* outp = (f32x4*)(out + (size_t)((b * HH + h + ph) * WW + w0) * OUTC);
        const f32x4* src4 = (const f32x4*)&out_lds[0][0];
#pragma unroll
        for (int it = 0; it < TAPS; ++it) {         // 9 iters, 1KB/wave each
            const int idx = wv * 576 + 64 * it + l; // contiguous across the wave
            __builtin_nontemporal_store(src4[idx], &outp[idx]);
        }

        // compiler-only fence: keep phase-2 ds_writes from moving above
        // phase-1 ds_reads (hardware DS pipe is in-order per wave).
        if (ph == 0) asm volatile("" ::: "memory");
    }
}

extern "C" void kernel_launch(void* const* d_in, const int* in_sizes, int n_in,
                              void* d_out, int out_size, void* d_ws, size_t ws_size,
                              hipStream_t stream) {
    const float* x = (const float*)d_in[0];
    float* out = (float*)d_out;
    const int nblocks = BB * (HH / HPB) * NTW;   // 8192
    patch3x3_v5<<<nblocks, 256, 0, stream>>>(x, out);
}